// Round 1
// baseline (721.939 us; speedup 1.0000x reference)
//
#include <hip/hip_runtime.h>
#include <math.h>

#define N_NODES 100000
#define N_EDGES 3200000

// ---------------------------------------------------------------------------
// gemm1: h[N,16] = x[N,512] @ W1[512,16]
// block = 256 threads handles 256 rows. LDS: k-major transposed x chunk
// xs[32][260] (pad 260 -> 4-way write conflict only; reads 2-way = free).
// Thread tile: 4 rows x 4 cols. W1 read from global (32KB, L1-resident).
// ---------------------------------------------------------------------------
__global__ __launch_bounds__(256) void gemm1_kernel(
    const float* __restrict__ x, const float* __restrict__ W1,
    float* __restrict__ h, int nrows)
{
    __shared__ float xs[32 * 260];
    const int t = threadIdx.x;
    const int rbase = blockIdx.x * 256;
    const int rq = t >> 2;      // 0..63  (row quad)
    const int cg = t & 3;       // 0..3   (col group of 4)

    float4 acc0 = make_float4(0.f, 0.f, 0.f, 0.f);
    float4 acc1 = acc0, acc2 = acc0, acc3 = acc0;

    const int kl4  = (t & 7) * 4;  // staging k offset within chunk (0,4,..,28)
    const int rstg = t >> 3;       // staging row base 0..31

    const float4* w4 = (const float4*)W1;   // W1 row = 16 floats = 4 float4

    for (int kc = 0; kc < 512; kc += 32) {
        // ---- stage x[rbase..rbase+256)[kc..kc+32) into xs[k][row] ----
        #pragma unroll
        for (int i = 0; i < 8; ++i) {
            int row = rstg + i * 32;
            int rg  = rbase + row;
            float4 v = make_float4(0.f, 0.f, 0.f, 0.f);
            if (rg < nrows)
                v = *(const float4*)(x + (size_t)rg * 512 + kc + kl4);
            xs[(kl4 + 0) * 260 + row] = v.x;
            xs[(kl4 + 1) * 260 + row] = v.y;
            xs[(kl4 + 2) * 260 + row] = v.z;
            xs[(kl4 + 3) * 260 + row] = v.w;
        }
        __syncthreads();

        // ---- compute: 32 k-steps ----
        #pragma unroll
        for (int k4 = 0; k4 < 8; ++k4) {
            const int k0 = k4 * 4;
            float4 xv0 = *(const float4*)(xs + (k0 + 0) * 260 + rq * 4);
            float4 xv1 = *(const float4*)(xs + (k0 + 1) * 260 + rq * 4);
            float4 xv2 = *(const float4*)(xs + (k0 + 2) * 260 + rq * 4);
            float4 xv3 = *(const float4*)(xs + (k0 + 3) * 260 + rq * 4);
            float4 wv0 = w4[(kc + k0 + 0) * 4 + cg];
            float4 wv1 = w4[(kc + k0 + 1) * 4 + cg];
            float4 wv2 = w4[(kc + k0 + 2) * 4 + cg];
            float4 wv3 = w4[(kc + k0 + 3) * 4 + cg];

            #define GCN_UPD(xv, wv)                                           \
                acc0.x += (xv).x * (wv).x; acc0.y += (xv).x * (wv).y;         \
                acc0.z += (xv).x * (wv).z; acc0.w += (xv).x * (wv).w;         \
                acc1.x += (xv).y * (wv).x; acc1.y += (xv).y * (wv).y;         \
                acc1.z += (xv).y * (wv).z; acc1.w += (xv).y * (wv).w;         \
                acc2.x += (xv).z * (wv).x; acc2.y += (xv).z * (wv).y;         \
                acc2.z += (xv).z * (wv).z; acc2.w += (xv).z * (wv).w;         \
                acc3.x += (xv).w * (wv).x; acc3.y += (xv).w * (wv).y;         \
                acc3.z += (xv).w * (wv).z; acc3.w += (xv).w * (wv).w;
            GCN_UPD(xv0, wv0)
            GCN_UPD(xv1, wv1)
            GCN_UPD(xv2, wv2)
            GCN_UPD(xv3, wv3)
            #undef GCN_UPD
        }
        __syncthreads();
    }

    // ---- epilogue: 4 rows x float4 of channels ----
    {
        int rg = rbase + rq * 4;
        if (rg + 0 < nrows) *(float4*)(h + (size_t)(rg + 0) * 16 + cg * 4) = acc0;
        if (rg + 1 < nrows) *(float4*)(h + (size_t)(rg + 1) * 16 + cg * 4) = acc1;
        if (rg + 2 < nrows) *(float4*)(h + (size_t)(rg + 2) * 16 + cg * 4) = acc2;
        if (rg + 3 < nrows) *(float4*)(h + (size_t)(rg + 3) * 16 + cg * 4) = acc3;
    }
}

// ---------------------------------------------------------------------------
// scatter16: agg[dst[e]][c] += feat[src[e]][c], one thread per (edge, channel)
// 16 lanes share an edge -> broadcast index loads, coalesced 64B feat reads,
// wave's 64 atomics land on 4 cache lines.
// ---------------------------------------------------------------------------
__global__ __launch_bounds__(256) void scatter16_kernel(
    const int* __restrict__ ei, const float* __restrict__ feat,
    float* __restrict__ agg)
{
    int g = blockIdx.x * 256 + threadIdx.x;
    int e = g >> 4;
    if (e >= N_EDGES) return;
    int c = g & 15;
    int s = ei[e];
    int d = ei[N_EDGES + e];
    atomicAdd(agg + (size_t)d * 16 + c, feat[(size_t)s * 16 + c]);
}

// ---------------------------------------------------------------------------
// bias_relu: h1 = relu(agg1 + b1), float4-wide elementwise
// ---------------------------------------------------------------------------
__global__ __launch_bounds__(256) void bias_relu_kernel(
    const float* __restrict__ agg1, const float* __restrict__ b1,
    float* __restrict__ h1)
{
    int i = blockIdx.x * 256 + threadIdx.x;     // float4 index
    if (i >= N_NODES * 4) return;
    float4 v = ((const float4*)agg1)[i];
    float4 b = ((const float4*)b1)[i & 3];
    v.x = fmaxf(v.x + b.x, 0.f);
    v.y = fmaxf(v.y + b.y, 0.f);
    v.z = fmaxf(v.z + b.z, 0.f);
    v.w = fmaxf(v.w + b.w, 0.f);
    ((float4*)h1)[i] = v;
}

// ---------------------------------------------------------------------------
// gemm2 + bias + log_softmax fused: out[row] = log_softmax(agg2[row] @ W2 + b2)
// one thread per row; W2 (16x40) + b2 staged in LDS.
// ---------------------------------------------------------------------------
__global__ __launch_bounds__(256) void gemm2_lsm_kernel(
    const float* __restrict__ agg2, const float* __restrict__ W2,
    const float* __restrict__ b2, float* __restrict__ out, int nrows)
{
    __shared__ float4 w2s[160];   // 16 x 40 floats = 160 float4
    __shared__ float4 b2s[10];    // 40 floats
    const int t = threadIdx.x;
    if (t < 160) w2s[t] = ((const float4*)W2)[t];
    else if (t < 170) b2s[t - 160] = ((const float4*)b2)[t - 160];
    __syncthreads();

    const int row = blockIdx.x * 256 + t;
    if (row >= nrows) return;

    float a[16];
    {
        const float4* ap = (const float4*)(agg2 + (size_t)row * 16);
        float4 a0 = ap[0], a1 = ap[1], a2 = ap[2], a3 = ap[3];
        a[0]=a0.x; a[1]=a0.y; a[2]=a0.z; a[3]=a0.w;
        a[4]=a1.x; a[5]=a1.y; a[6]=a1.z; a[7]=a1.w;
        a[8]=a2.x; a[9]=a2.y; a[10]=a2.z; a[11]=a2.w;
        a[12]=a3.x; a[13]=a3.y; a[14]=a3.z; a[15]=a3.w;
    }

    float4 z[10];
    #pragma unroll
    for (int c4 = 0; c4 < 10; ++c4) z[c4] = b2s[c4];

    #pragma unroll
    for (int k = 0; k < 16; ++k) {
        const float av = a[k];
        #pragma unroll
        for (int c4 = 0; c4 < 10; ++c4) {
            float4 w = w2s[k * 10 + c4];
            z[c4].x += av * w.x;
            z[c4].y += av * w.y;
            z[c4].z += av * w.z;
            z[c4].w += av * w.w;
        }
    }

    float m = z[0].x;
    #pragma unroll
    for (int c4 = 0; c4 < 10; ++c4) {
        m = fmaxf(m, z[c4].x); m = fmaxf(m, z[c4].y);
        m = fmaxf(m, z[c4].z); m = fmaxf(m, z[c4].w);
    }
    float s = 0.f;
    #pragma unroll
    for (int c4 = 0; c4 < 10; ++c4) {
        s += __expf(z[c4].x - m); s += __expf(z[c4].y - m);
        s += __expf(z[c4].z - m); s += __expf(z[c4].w - m);
    }
    const float lse = m + __logf(s);

    float4* op = (float4*)(out + (size_t)row * 40);
    #pragma unroll
    for (int c4 = 0; c4 < 10; ++c4) {
        float4 o;
        o.x = z[c4].x - lse; o.y = z[c4].y - lse;
        o.z = z[c4].z - lse; o.w = z[c4].w - lse;
        op[c4] = o;
    }
}

// ---------------------------------------------------------------------------
extern "C" void kernel_launch(void* const* d_in, const int* in_sizes, int n_in,
                              void* d_out, int out_size, void* d_ws, size_t ws_size,
                              hipStream_t stream)
{
    const float* x  = (const float*)d_in[0];
    const int*   ei = (const int*)d_in[1];    // edge_index [2, E]
    const float* W1 = (const float*)d_in[2];
    const float* b1 = (const float*)d_in[3];
    const float* W2 = (const float*)d_in[4];
    const float* b2 = (const float*)d_in[5];
    float* out = (float*)d_out;

    // ws layout: bufA = h / h1, bufB = agg1 / agg2  (each N*16 floats)
    float* bufA = (float*)d_ws;
    float* bufB = bufA + (size_t)N_NODES * 16;
    const size_t aggBytes = (size_t)N_NODES * 16 * sizeof(float);

    const int gemm1_blocks = (N_NODES + 255) / 256;          // 391
    const int scat_blocks  = (N_EDGES * 16) / 256;           // 200000
    const int relu_blocks  = (N_NODES * 4 + 255) / 256;      // 1563

    // conv1
    hipMemsetAsync(bufB, 0, aggBytes, stream);
    gemm1_kernel<<<gemm1_blocks, 256, 0, stream>>>(x, W1, bufA, N_NODES);
    scatter16_kernel<<<scat_blocks, 256, 0, stream>>>(ei, bufA, bufB);
    bias_relu_kernel<<<relu_blocks, 256, 0, stream>>>(bufB, b1, bufA);

    // conv2 (linear: scatter h1 first, apply W2 after aggregation) + log_softmax
    hipMemsetAsync(bufB, 0, aggBytes, stream);
    scatter16_kernel<<<scat_blocks, 256, 0, stream>>>(ei, bufA, bufB);
    gemm2_lsm_kernel<<<gemm1_blocks, 256, 0, stream>>>(bufB, W2, b2, out, N_NODES);
}